// Round 1
// baseline (230.222 us; speedup 1.0000x reference)
//
#include <hip/hip_runtime.h>
#include <hip/hip_bf16.h>

#define HH 512
#define WW 512
#define CIN 256
#define COUT 256
#define NPTS 65536
#define KTOT 2304   // 256*9, reordered as k' = t*256 + ci

typedef __bf16 bf16x8 __attribute__((ext_vector_type(8)));
typedef float f32x4 __attribute__((ext_vector_type(4)));
typedef unsigned short us8 __attribute__((ext_vector_type(8)));

static __device__ __forceinline__ unsigned short f2bf(float f) {
  unsigned u = __builtin_bit_cast(unsigned, f);
  unsigned r = u + 0x7fffu + ((u >> 16) & 1u);
  return (unsigned short)(r >> 16);
}

// A_bf[co][t*256 + ci] = bf16(weight[co][ci*9 + t])
__global__ __launch_bounds__(256) void prep_weight(const float* __restrict__ w,
                                                   unsigned short* __restrict__ A) {
  int i = blockIdx.x * 256 + threadIdx.x;   // i = co*2304 + t*256 + ci
  int co = i / 2304;
  int r  = i - co * 2304;
  int t  = r >> 8;
  int ci = r & 255;
  A[i] = f2bf(w[co * 2304 + ci * 9 + t]);
}

// Ft[(y*512+x)*256 + ci] = bf16(feature[ci][y][x]); tiled transpose via LDS
__global__ __launch_bounds__(256) void transpose_feat(const float* __restrict__ f,
                                                      unsigned short* __restrict__ Ft) {
  __shared__ unsigned short lds[64 * 264];   // 64 pixels x 256 ci, row stride 264 (16B-aligned rows)
  int pix0 = blockIdx.x * 64;
  int tid = threadIdx.x;
  int p = tid & 63;          // pixel within tile
  int cb = tid >> 6;         // 0..3 : 64-channel group
  const float* src = f + pix0 + p;
  for (int c8 = 0; c8 < 8; ++c8) {
    us8 v;
#pragma unroll
    for (int j = 0; j < 8; ++j) {
      int ci = cb * 64 + c8 * 8 + j;
      v[j] = f2bf(src[ci * 262144]);   // coalesced across lanes (p contiguous)
    }
    *(us8*)&lds[p * 264 + cb * 64 + c8 * 8] = v;
  }
  __syncthreads();
  int cic = tid & 31;        // 32 chunks of 8 channels
  int pr = tid >> 5;         // 0..7
  for (int g = 0; g < 8; ++g) {
    int p2 = pr + g * 8;
    us8 v = *(const us8*)&lds[p2 * 264 + cic * 8];
    *(us8*)&Ft[(size_t)(pix0 + p2) * 256 + cic * 8] = v;   // 512B contiguous per 32 lanes
  }
}

// C[256][65536] = A[256][2304] * B[2304][65536], B gathered from Ft on the fly.
__global__ __launch_bounds__(512) void gemm_gather(
    const unsigned short* __restrict__ A,    // bf16 bits [COUT][KTOT], k' = t*256+ci
    const unsigned short* __restrict__ Ft,   // bf16 bits [512*512][256]
    const int* __restrict__ hidx,            // rows of (9,N); row 0 = base_h
    const int* __restrict__ widx,
    float* __restrict__ out) {
  __shared__ unsigned short Asm[256 * 40];   // 32 k + 8 pad per row (80B stride)
  __shared__ unsigned short Bsm[64 * 40];
  __shared__ int sy[64];
  __shared__ int sx[64];

  int tid = threadIdx.x;
  int n0 = blockIdx.x * 64;
  if (tid < 64) sy[tid] = hidx[n0 + tid];
  if (tid >= 64 && tid < 128) sx[tid - 64] = widx[n0 + tid - 64];
  __syncthreads();

  int lane = tid & 63;
  int wv = tid >> 6;      // 0..7
  int m0 = wv * 32;

  f32x4 acc[2][4];
#pragma unroll
  for (int mi = 0; mi < 2; ++mi)
#pragma unroll
    for (int nj = 0; nj < 4; ++nj)
      acc[mi][nj] = (f32x4){0.f, 0.f, 0.f, 0.f};

  int aco = tid >> 2;     // 0..127 (A row, +128 for second chunk)
  int ach = tid & 3;      // 16B chunk within 32-k row
  int bn = tid >> 2;      // 0..63  (B column) when tid<256
  int bch = tid & 3;

  for (int kk = 0; kk < 72; ++kk) {
    int t = kk >> 3;                 // 0..8, wave-uniform
    int ci0 = (kk & 7) << 5;         // 0,32,...,224
    // ---- global loads (to regs) ----
    us8 a0 = *(const us8*)&A[(size_t)aco * KTOT + kk * 32 + ach * 8];
    us8 a1 = *(const us8*)&A[(size_t)(aco + 128) * KTOT + kk * 32 + ach * 8];
    us8 b = {0, 0, 0, 0, 0, 0, 0, 0};
    if (tid < 256) {
      int y = sy[bn] + (t / 3) - 1;
      int x = sx[bn] + (t % 3) - 1;
      if ((unsigned)y < 512u && (unsigned)x < 512u) {
        b = *(const us8*)&Ft[(size_t)((y << 9) | x) * 256 + ci0 + bch * 8];
      }
    }
    __syncthreads();   // previous iteration's frag reads done
    *(us8*)&Asm[aco * 40 + ach * 8] = a0;
    *(us8*)&Asm[(aco + 128) * 40 + ach * 8] = a1;
    if (tid < 256) *(us8*)&Bsm[bn * 40 + bch * 8] = b;
    __syncthreads();
    // ---- fragments + MFMA ----
    bf16x8 af[2], bfr[4];
#pragma unroll
    for (int mi = 0; mi < 2; ++mi)
      af[mi] = *(const bf16x8*)&Asm[(m0 + mi * 16 + (lane & 15)) * 40 + (lane >> 4) * 8];
#pragma unroll
    for (int nj = 0; nj < 4; ++nj)
      bfr[nj] = *(const bf16x8*)&Bsm[(nj * 16 + (lane & 15)) * 40 + (lane >> 4) * 8];
#pragma unroll
    for (int mi = 0; mi < 2; ++mi)
#pragma unroll
      for (int nj = 0; nj < 4; ++nj)
        acc[mi][nj] = __builtin_amdgcn_mfma_f32_16x16x32_bf16(af[mi], bfr[nj], acc[mi][nj], 0, 0, 0);
  }

  // epilogue: D col = lane&15, row = (lane>>4)*4 + r
  int col = n0 + (lane & 15);
  int r0 = (lane >> 4) * 4;
#pragma unroll
  for (int mi = 0; mi < 2; ++mi)
#pragma unroll
    for (int nj = 0; nj < 4; ++nj)
#pragma unroll
      for (int r = 0; r < 4; ++r) {
        int row = m0 + mi * 16 + r0 + r;
        out[(size_t)row * NPTS + col + nj * 16] = acc[mi][nj][r];
      }
}

// Safety-net path if workspace is too small: direct conv, fp32.
__global__ __launch_bounds__(256) void naive_conv(const float* __restrict__ f,
                                                  const float* __restrict__ w,
                                                  const int* __restrict__ hi,
                                                  const int* __restrict__ wi,
                                                  float* __restrict__ out) {
  int idx = blockIdx.x * 256 + threadIdx.x;
  int n = idx & (NPTS - 1);
  int co = idx >> 16;
  int bh = hi[n] - 1;
  int bw = wi[n] - 1;
  float acc = 0.f;
  for (int ci = 0; ci < CIN; ++ci) {
    const float* fc = f + (size_t)ci * 262144;
    const float* wc = w + (size_t)co * 2304 + ci * 9;
#pragma unroll
    for (int t = 0; t < 9; ++t) {
      int y = bh + t / 3, x = bw + t % 3;
      float v = (y >= 0 && y < 512 && x >= 0 && x < 512) ? fc[y * 512 + x] : 0.f;
      acc += wc[t] * v;
    }
  }
  out[(size_t)co * NPTS + n] = acc;
}

extern "C" void kernel_launch(void* const* d_in, const int* in_sizes, int n_in,
                              void* d_out, int out_size, void* d_ws, size_t ws_size,
                              hipStream_t stream) {
  const float* feature = (const float*)d_in[0];
  const float* weight  = (const float*)d_in[1];
  const int* hidx      = (const int*)d_in[2];
  const int* widx      = (const int*)d_in[3];
  float* out           = (float*)d_out;

  const size_t FT_OFF = 2ull * 1024 * 1024;
  const size_t FT_BYTES = (size_t)262144 * 256 * 2;     // 128 MiB
  const size_t NEED = FT_OFF + FT_BYTES;                // ~130 MiB

  if (ws_size >= NEED) {
    unsigned short* Abf = (unsigned short*)d_ws;        // 1.13 MiB
    unsigned short* Ft = (unsigned short*)((char*)d_ws + FT_OFF);
    prep_weight<<<(COUT * KTOT) / 256, 256, 0, stream>>>(weight, Abf);
    transpose_feat<<<262144 / 64, 256, 0, stream>>>(feature, Ft);
    gemm_gather<<<NPTS / 64, 512, 0, stream>>>(Abf, Ft, hidx, widx, out);
  } else {
    naive_conv<<<(COUT * NPTS) / 256, 256, 0, stream>>>(feature, weight, hidx, widx, out);
  }
}

// Round 2
// 191.306 us; speedup vs baseline: 1.2034x; 1.2034x over previous
//
#include <hip/hip_runtime.h>
#include <hip/hip_bf16.h>

#define HH 512
#define WW 512
#define CIN 256
#define COUT 256
#define NPTS 65536
#define KTOT 2304
#define PW 514                       // padded image width/height
#define NPIX (PW * PW)

typedef __bf16 bf16x8 __attribute__((ext_vector_type(8)));
typedef float f32x4 __attribute__((ext_vector_type(4)));
typedef unsigned short us8 __attribute__((ext_vector_type(8)));

static __device__ __forceinline__ unsigned short f2bf(float f) {
  unsigned u = __builtin_bit_cast(unsigned, f);
  unsigned r = u + 0x7fffu + ((u >> 16) & 1u);
  return (unsigned short)(r >> 16);
}

static __device__ __forceinline__ void gload16(const void* g, void* l) {
  __builtin_amdgcn_global_load_lds(
      (const __attribute__((address_space(1))) unsigned int*)g,
      (__attribute__((address_space(3))) unsigned int*)l, 16, 0, 0);
}

// Abf[kk*8192 + co*32 + pc*8 + j] = bf16(w[co][ci*9+t]) where the *logical*
// k-chunk is lc = pc ^ ((co>>1)&3)  (bank-conflict swizzle baked into global
// layout so linear global_load_lds produces the swizzled LDS tile), and
// k' = kk*32 + lc*8 + j with k' = t*256 + ci.
__global__ __launch_bounds__(256) void prep_weight(const float* __restrict__ w,
                                                   unsigned short* __restrict__ A) {
  int i = blockIdx.x * 256 + threadIdx.x;       // 72*256*32 = 589824 total
  int j  = i & 7;
  int pc = (i >> 3) & 3;
  int co = (i >> 5) & 255;
  int kk = i >> 13;
  int lc = pc ^ ((co >> 1) & 3);
  int k  = kk * 32 + lc * 8 + j;                // k' = t*256 + ci
  int t  = k >> 8;
  int ci = k & 255;
  A[i] = f2bf(w[co * 2304 + ci * 9 + t]);
}

// Zero the border ring of the padded (514x514) bf16 feature image.
__global__ __launch_bounds__(256) void border_zero(unsigned short* __restrict__ Ft) {
  int g = blockIdx.x * 256 + threadIdx.x;
  if (g >= 2052 * 32) return;
  int p = g >> 5, c = g & 31;
  int py, px;
  if (p < 514)        { py = 0;        px = p; }
  else if (p < 1028)  { py = 513;      px = p - 514; }
  else if (p < 1540)  { py = p - 1027; px = 0; }
  else                { py = p - 1539; px = 513; }
  *(us8*)&Ft[((size_t)py * PW + px) * 256 + c * 8] = (us8){0, 0, 0, 0, 0, 0, 0, 0};
}

// Ft[((y+1)*514 + (x+1))*256 + ci] = bf16(feature[ci][y][x])
__global__ __launch_bounds__(256) void transpose_feat(const float* __restrict__ f,
                                                      unsigned short* __restrict__ Ft) {
  __shared__ unsigned short lds[64 * 264];
  int pix0 = blockIdx.x * 64;
  int y = pix0 >> 9, x0 = pix0 & 511;
  int tid = threadIdx.x;
  int p = tid & 63;
  int cb = tid >> 6;
  const float* src = f + pix0 + p;
  for (int c8 = 0; c8 < 8; ++c8) {
    us8 v;
#pragma unroll
    for (int j = 0; j < 8; ++j) {
      int ci = cb * 64 + c8 * 8 + j;
      v[j] = f2bf(src[ci * 262144]);
    }
    *(us8*)&lds[p * 264 + cb * 64 + c8 * 8] = v;
  }
  __syncthreads();
  int cic = tid & 31;
  int pr = tid >> 5;
  for (int g = 0; g < 8; ++g) {
    int p2 = pr + g * 8;
    us8 v = *(const us8*)&lds[p2 * 264 + cic * 8];
    *(us8*)&Ft[((size_t)((y + 1) * PW + x0 + 1 + p2)) * 256 + cic * 8] = v;
  }
}

// C[256][65536] = A[256][2304] * gathered-B. BM=256, BN=128, BK=32,
// 8 waves (4M x 2N), wave tile 64x64, global_load_lds double-buffered.
__global__ __launch_bounds__(512) void gemm_gather(
    const unsigned short* __restrict__ A,     // [72][256][32] swizzled bf16
    const unsigned short* __restrict__ Ft,    // [514*514][256] bf16 padded
    const int* __restrict__ hidx,
    const int* __restrict__ widx,
    float* __restrict__ out) {
  __shared__ unsigned short Asm[2 * 256 * 32];   // 32 KiB
  __shared__ unsigned short Bsm[2 * 128 * 32];   // 16 KiB

  int tid = threadIdx.x;
  int n0 = blockIdx.x * 128;
  int lane = tid & 63, wv = tid >> 6;
  int m0 = (wv & 3) * 64;        // wave row block (4 waves over M=256)
  int nw0 = (wv >> 2) * 64;      // wave col block (2 waves over BN=128)

  // B-gather mapping: thread -> (column, physical 16B chunk)
  int col = tid >> 2;            // 0..127
  int pc  = tid & 3;
  int lc  = pc ^ ((col >> 1) & 3);                 // logical chunk to fetch
  int p0  = hidx[n0 + col] * PW + widx[n0 + col];  // padded base pixel
  const unsigned short* FtT = Ft + (size_t)p0 * 256 + lc * 8;

  f32x4 acc[4][4];
#pragma unroll
  for (int mi = 0; mi < 4; ++mi)
#pragma unroll
    for (int nj = 0; nj < 4; ++nj)
      acc[mi][nj] = (f32x4){0.f, 0.f, 0.f, 0.f};

  unsigned short* AsmW = &Asm[wv * 512];   // wave-uniform DMA bases
  unsigned short* BsmW = &Bsm[wv * 512];

  // ---- staging (global_load_lds, 16B/lane) ----
  // A: two passes, fully linear. B: per-lane gathered source, linear dest.
#define STAGE(BUF, KK)                                                        \
  do {                                                                        \
    const unsigned short* ga = A + (size_t)(KK) * 8192 + tid * 8;             \
    gload16(ga, AsmW + (BUF) * 8192);                                         \
    gload16(ga + 4096, AsmW + (BUF) * 8192 + 4096);                           \
    int t_ = (KK) >> 3;                                                       \
    int q_ = t_ / 3;                                                          \
    int dt_ = q_ * PW + (t_ - q_ * 3);                                        \
    int ci0_ = ((KK) & 7) * 32;                                               \
    gload16(FtT + (size_t)dt_ * 256 + ci0_, BsmW + (BUF) * 4096);             \
  } while (0)

  STAGE(0, 0);
  __syncthreads();

  int cur = 0;
  for (int kk = 0; kk < 72; ++kk) {
    if (kk + 1 < 72) STAGE(cur ^ 1, kk + 1);

    bf16x8 af[4], bfr[4];
#pragma unroll
    for (int mi = 0; mi < 4; ++mi) {
      int row = m0 + mi * 16 + (lane & 15);
      int ch = (lane >> 4) ^ ((row >> 1) & 3);
      af[mi] = *(const bf16x8*)&Asm[cur * 8192 + row * 32 + ch * 8];
    }
#pragma unroll
    for (int nj = 0; nj < 4; ++nj) {
      int ccol = nw0 + nj * 16 + (lane & 15);
      int ch = (lane >> 4) ^ ((ccol >> 1) & 3);
      bfr[nj] = *(const bf16x8*)&Bsm[cur * 4096 + ccol * 32 + ch * 8];
    }
#pragma unroll
    for (int mi = 0; mi < 4; ++mi)
#pragma unroll
      for (int nj = 0; nj < 4; ++nj)
        acc[mi][nj] = __builtin_amdgcn_mfma_f32_16x16x32_bf16(af[mi], bfr[nj], acc[mi][nj], 0, 0, 0);

    __syncthreads();   // drains vmcnt (stage) + lgkmcnt before buffer swap
    cur ^= 1;
  }
#undef STAGE

  // epilogue: D col = lane&15, row = (lane>>4)*4 + r
  int ocol = n0 + nw0 + (lane & 15);
  int r0 = (lane >> 4) * 4;
#pragma unroll
  for (int mi = 0; mi < 4; ++mi)
#pragma unroll
    for (int nj = 0; nj < 4; ++nj)
#pragma unroll
      for (int r = 0; r < 4; ++r)
        out[(size_t)(m0 + mi * 16 + r0 + r) * NPTS + ocol + nj * 16] = acc[mi][nj][r];
}

// Safety-net path if workspace is too small: direct conv, fp32.
__global__ __launch_bounds__(256) void naive_conv(const float* __restrict__ f,
                                                  const float* __restrict__ w,
                                                  const int* __restrict__ hi,
                                                  const int* __restrict__ wi,
                                                  float* __restrict__ out) {
  int idx = blockIdx.x * 256 + threadIdx.x;
  int n = idx & (NPTS - 1);
  int co = idx >> 16;
  int bh = hi[n] - 1;
  int bw = wi[n] - 1;
  float acc = 0.f;
  for (int ci = 0; ci < CIN; ++ci) {
    const float* fc = f + (size_t)ci * 262144;
    const float* wc = w + (size_t)co * 2304 + ci * 9;
#pragma unroll
    for (int t = 0; t < 9; ++t) {
      int y = bh + t / 3, x = bw + t % 3;
      float v = (y >= 0 && y < 512 && x >= 0 && x < 512) ? fc[y * 512 + x] : 0.f;
      acc += wc[t] * v;
    }
  }
  out[(size_t)co * NPTS + n] = acc;
}

extern "C" void kernel_launch(void* const* d_in, const int* in_sizes, int n_in,
                              void* d_out, int out_size, void* d_ws, size_t ws_size,
                              hipStream_t stream) {
  const float* feature = (const float*)d_in[0];
  const float* weight  = (const float*)d_in[1];
  const int* hidx      = (const int*)d_in[2];
  const int* widx      = (const int*)d_in[3];
  float* out           = (float*)d_out;

  const size_t FT_OFF = 2ull * 1024 * 1024;
  const size_t FT_BYTES = (size_t)NPIX * 256 * 2;   // ~135 MiB
  const size_t NEED = FT_OFF + FT_BYTES;

  if (ws_size >= NEED) {
    unsigned short* Abf = (unsigned short*)d_ws;
    unsigned short* Ft = (unsigned short*)((char*)d_ws + FT_OFF);
    prep_weight<<<(72 * 256 * 32) / 256, 256, 0, stream>>>(weight, Abf);
    border_zero<<<(2052 * 32 + 255) / 256, 256, 0, stream>>>(Ft);
    transpose_feat<<<262144 / 64, 256, 0, stream>>>(feature, Ft);
    gemm_gather<<<NPTS / 128, 512, 0, stream>>>(Abf, Ft, hidx, widx, out);
  } else {
    naive_conv<<<(COUT * NPTS) / 256, 256, 0, stream>>>(feature, weight, hidx, widx, out);
  }
}

// Round 3
// 175.954 us; speedup vs baseline: 1.3084x; 1.0873x over previous
//
#include <hip/hip_runtime.h>
#include <hip/hip_bf16.h>

#define HH 512
#define WW 512
#define CIN 256
#define COUT 256
#define NPTS 65536
#define PW 514
#define NPIX (PW * PW)
#define NKT 36                      // K tiles of 64 (total K = 2304)

typedef __bf16 bf16x8 __attribute__((ext_vector_type(8)));
typedef float f32x4 __attribute__((ext_vector_type(4)));
typedef unsigned short us8 __attribute__((ext_vector_type(8)));

static __device__ __forceinline__ unsigned short f2bf(float f) {
  unsigned u = __builtin_bit_cast(unsigned, f);
  unsigned r = u + 0x7fffu + ((u >> 16) & 1u);
  return (unsigned short)(r >> 16);
}

static __device__ __forceinline__ void gload16(const void* g, void* l) {
  __builtin_amdgcn_global_load_lds(
      (const __attribute__((address_space(1))) unsigned int*)g,
      (__attribute__((address_space(3))) unsigned int*)l, 16, 0, 0);
}

// Aprep layout: i = kb*16384 + s*8192 + o, o in [0,8192):
//   r = o>>5 (co), c' = (o>>3)&3, j = o&7, c = c' ^ ((r>>1)&3)
//   k = kb*64 + s*32 + c*8 + j  (k = t*256 + ci ordering)
// so a linear global_load_lds of 8192 shorts produces the swizzled LDS chunk.
__global__ __launch_bounds__(256) void prep_weight(const float* __restrict__ w,
                                                   unsigned short* __restrict__ A) {
  int i = blockIdx.x * 256 + threadIdx.x;       // 36*16384 = 589824 total
  int kb = i >> 14;
  int s  = (i >> 13) & 1;
  int o  = i & 8191;
  int r  = o >> 5;
  int cp = (o >> 3) & 3;
  int j  = o & 7;
  int c  = cp ^ ((r >> 1) & 3);
  int k  = kb * 64 + s * 32 + c * 8 + j;
  int t  = k >> 8;
  int ci = k & 255;
  A[i] = f2bf(w[r * 2304 + ci * 9 + t]);
}

// Zero the border ring of the padded (514x514) bf16 feature image.
__global__ __launch_bounds__(256) void border_zero(unsigned short* __restrict__ Ft) {
  int g = blockIdx.x * 256 + threadIdx.x;
  if (g >= 2052 * 32) return;
  int p = g >> 5, c = g & 31;
  int py, px;
  if (p < 514)        { py = 0;        px = p; }
  else if (p < 1028)  { py = 513;      px = p - 514; }
  else if (p < 1540)  { py = p - 1027; px = 0; }
  else                { py = p - 1539; px = 513; }
  *(us8*)&Ft[((size_t)py * PW + px) * 256 + c * 8] = (us8){0, 0, 0, 0, 0, 0, 0, 0};
}

// Ft[((y+1)*514 + (x+1))*256 + ci] = bf16(feature[ci][y][x])
__global__ __launch_bounds__(256) void transpose_feat(const float* __restrict__ f,
                                                      unsigned short* __restrict__ Ft) {
  __shared__ unsigned short lds[64 * 264];
  int pix0 = blockIdx.x * 64;
  int y = pix0 >> 9, x0 = pix0 & 511;
  int tid = threadIdx.x;
  int p = tid & 63;
  int cb = tid >> 6;
  const float* src = f + pix0 + p;
  for (int c8 = 0; c8 < 8; ++c8) {
    us8 v;
#pragma unroll
    for (int j = 0; j < 8; ++j) {
      int ci = cb * 64 + c8 * 8 + j;
      v[j] = f2bf(src[ci * 262144]);
    }
    *(us8*)&lds[p * 264 + cb * 64 + c8 * 8] = v;
  }
  __syncthreads();
  int cic = tid & 31;
  int pr = tid >> 5;
  for (int g = 0; g < 8; ++g) {
    int p2 = pr + g * 8;
    us8 v = *(const us8*)&lds[p2 * 264 + cic * 8];
    *(us8*)&Ft[((size_t)((y + 1) * PW + x0 + 1 + p2)) * 256 + cic * 8] = v;
  }
}

// 256x256x(K=2304) gather-GEMM, 4-phase/K-tile counted-vmcnt pipeline.
// 8 waves = 2M x 4N, wave tile 128x64. LDS: A 2x2x8192, B same (128 KiB).
__global__ __launch_bounds__(512, 2) void gemm_gather(
    const unsigned short* __restrict__ A,     // Aprep, swizzle baked in
    const unsigned short* __restrict__ Ft,    // [514*514][256] bf16 padded
    const int* __restrict__ hidx,
    const int* __restrict__ widx,
    float* __restrict__ out) {
  __shared__ unsigned short lds[65536];       // [0,32768) = A, [32768,65536) = B
  unsigned short* ldsB = lds + 32768;

  int tid = threadIdx.x;
  int lane = tid & 63, wv = tid >> 6;
  int wm = wv & 1, wn = wv >> 1;
  int n0 = blockIdx.x << 8;

  // B staging constants: thread covers cols c0 (pass0) and 128+c0 (pass1),
  // logical ci-chunk cc = (tid&3) ^ key(col) with key(col) = (col>>1)&3.
  int c0 = tid >> 2;
  int cc = (tid & 3) ^ ((tid >> 3) & 3);
  long pixA = (long)hidx[n0 + c0] * PW + widx[n0 + c0];
  long pixB = (long)hidx[n0 + 128 + c0] * PW + widx[n0 + 128 + c0];
  const unsigned short* FtB0 = Ft + pixA * 256 + cc * 8;
  const unsigned short* FtB1 = Ft + pixB * 256 + cc * 8;

#define STAGE_A(dbuf, kb_, s_)                                                \
  do {                                                                        \
    const unsigned short* g_ = A + (kb_) * 16384 + (s_) * 8192 + tid * 8;     \
    unsigned short* l_ = lds + (dbuf) * 16384 + (s_) * 8192 + tid * 8;        \
    gload16(g_, l_);                                                          \
    gload16(g_ + 4096, l_ + 4096);                                            \
  } while (0)

#define STAGE_B(dbuf, s_, base_)                                              \
  do {                                                                        \
    unsigned short* l_ = ldsB + (dbuf) * 16384 + (s_) * 8192 + tid * 8;       \
    gload16(FtB0 + (base_) + (s_) * 32, l_);                                  \
    gload16(FtB1 + (base_) + (s_) * 32, l_ + 4096);                           \
  } while (0)

#define LDA(dst, dbuf, s_, mi_)                                               \
  do {                                                                        \
    int r_ = wm * 128 + (mi_) * 16 + (lane & 15);                             \
    int cp_ = (lane >> 4) ^ ((r_ >> 1) & 3);                                  \
    dst = *(const bf16x8*)&lds[(dbuf) * 16384 + (s_) * 8192 + r_ * 32 + cp_ * 8]; \
  } while (0)

#define LDB(dst, dbuf, s_, nj_)                                               \
  do {                                                                        \
    int col_ = wn * 64 + (nj_) * 16 + (lane & 15);                            \
    int cp_ = (lane >> 4) ^ ((col_ >> 1) & 3);                                \
    dst = *(const bf16x8*)&ldsB[(dbuf) * 16384 + (s_) * 8192 + col_ * 32 + cp_ * 8]; \
  } while (0)

#define MFMA16(mq_)                                                           \
  do {                                                                        \
    __builtin_amdgcn_s_setprio(1);                                            \
    _Pragma("unroll") for (int mi = 0; mi < 4; ++mi)                          \
        _Pragma("unroll") for (int nj = 0; nj < 4; ++nj)                      \
            acc[(mq_) * 4 + mi][nj] = __builtin_amdgcn_mfma_f32_16x16x32_bf16( \
                af[mi], bfr[nj], acc[(mq_) * 4 + mi][nj], 0, 0, 0);           \
    __builtin_amdgcn_s_setprio(0);                                            \
  } while (0)

  f32x4 acc[8][4];
#pragma unroll
  for (int mi = 0; mi < 8; ++mi)
#pragma unroll
    for (int nj = 0; nj < 4; ++nj)
      acc[mi][nj] = (f32x4){0.f, 0.f, 0.f, 0.f};

  // ---- prologue: stage K-tile 0 into buf 0 (order As0, Bs0, As1, Bs1) ----
  STAGE_A(0, 0, 0);
  STAGE_B(0, 0, 0);       // kb=0: tap 0 -> dt=0, ci base 0
  STAGE_A(0, 0, 1);
  STAGE_B(0, 1, 0);
  asm volatile("s_waitcnt vmcnt(4)" ::: "memory");  // As0,Bs0 resident
  __builtin_amdgcn_s_barrier();

  for (int kb = 0; kb < NKT - 1; ++kb) {
    int d = kb & 1;
    int kn = kb + 1;
    int tp = kn >> 2;
    int q3 = tp / 3;
    int dtb = (q3 * PW + (tp - q3 * 3)) * 256 + (kn & 3) * 64;

    bf16x8 af[4], bfr[4];
    // phase 0: (m-half 0, k-half 0); stage As0(t+1)
    LDA(af[0], d, 0, 0); LDA(af[1], d, 0, 1); LDA(af[2], d, 0, 2); LDA(af[3], d, 0, 3);
    LDB(bfr[0], d, 0, 0); LDB(bfr[1], d, 0, 1); LDB(bfr[2], d, 0, 2); LDB(bfr[3], d, 0, 3);
    STAGE_A(d ^ 1, kn, 0);
    __builtin_amdgcn_s_barrier();
    MFMA16(0);
    __builtin_amdgcn_s_barrier();
    // phase 1: (m-half 1, k-half 0); stage Bs0(t+1); vmcnt(4) => tile t fully resident
    LDA(af[0], d, 0, 4); LDA(af[1], d, 0, 5); LDA(af[2], d, 0, 6); LDA(af[3], d, 0, 7);
    STAGE_B(d ^ 1, 0, dtb);
    __builtin_amdgcn_s_barrier();
    MFMA16(1);
    asm volatile("s_waitcnt vmcnt(4)" ::: "memory");
    __builtin_amdgcn_s_barrier();
    // phase 2: (m-half 0, k-half 1); stage As1(t+1)
    LDA(af[0], d, 1, 0); LDA(af[1], d, 1, 1); LDA(af[2], d, 1, 2); LDA(af[3], d, 1, 3);
    LDB(bfr[0], d, 1, 0); LDB(bfr[1], d, 1, 1); LDB(bfr[2], d, 1, 2); LDB(bfr[3], d, 1, 3);
    STAGE_A(d ^ 1, kn, 1);
    __builtin_amdgcn_s_barrier();
    MFMA16(0);
    __builtin_amdgcn_s_barrier();
    // phase 3: (m-half 1, k-half 1); stage Bs1(t+1); vmcnt(4) => As0,Bs0(t+1) resident
    LDA(af[0], d, 1, 4); LDA(af[1], d, 1, 5); LDA(af[2], d, 1, 6); LDA(af[3], d, 1, 7);
    STAGE_B(d ^ 1, 1, dtb);
    __builtin_amdgcn_s_barrier();
    MFMA16(1);
    asm volatile("s_waitcnt vmcnt(4)" ::: "memory");
    __builtin_amdgcn_s_barrier();
  }

  // ---- peeled last tile (kb = 35, buf 1), no staging ----
  {
    const int d = (NKT - 1) & 1;
    bf16x8 af[4], bfr[4];
    LDA(af[0], d, 0, 0); LDA(af[1], d, 0, 1); LDA(af[2], d, 0, 2); LDA(af[3], d, 0, 3);
    LDB(bfr[0], d, 0, 0); LDB(bfr[1], d, 0, 1); LDB(bfr[2], d, 0, 2); LDB(bfr[3], d, 0, 3);
    __builtin_amdgcn_s_barrier();
    MFMA16(0);
    __builtin_amdgcn_s_barrier();
    LDA(af[0], d, 0, 4); LDA(af[1], d, 0, 5); LDA(af[2], d, 0, 6); LDA(af[3], d, 0, 7);
    __builtin_amdgcn_s_barrier();
    MFMA16(1);
    asm volatile("s_waitcnt vmcnt(0)" ::: "memory");  // drain: As1,Bs1 of last tile
    __builtin_amdgcn_s_barrier();
    LDA(af[0], d, 1, 0); LDA(af[1], d, 1, 1); LDA(af[2], d, 1, 2); LDA(af[3], d, 1, 3);
    LDB(bfr[0], d, 1, 0); LDB(bfr[1], d, 1, 1); LDB(bfr[2], d, 1, 2); LDB(bfr[3], d, 1, 3);
    __builtin_amdgcn_s_barrier();
    MFMA16(0);
    __builtin_amdgcn_s_barrier();
    LDA(af[0], d, 1, 4); LDA(af[1], d, 1, 5); LDA(af[2], d, 1, 6); LDA(af[3], d, 1, 7);
    __builtin_amdgcn_s_barrier();
    MFMA16(1);
  }

  // ---- epilogue: D col = lane&15, row = (lane>>4)*4 + r ----
  int ocol = n0 + wn * 64 + (lane & 15);
  int r0 = (lane >> 4) * 4;
#pragma unroll
  for (int mi = 0; mi < 8; ++mi)
#pragma unroll
    for (int nj = 0; nj < 4; ++nj)
#pragma unroll
      for (int r = 0; r < 4; ++r)
        out[(size_t)(wm * 128 + mi * 16 + r0 + r) * NPTS + ocol + nj * 16] = acc[mi][nj][r];

#undef STAGE_A
#undef STAGE_B
#undef LDA
#undef LDB
#undef MFMA16
}

// Safety-net path if workspace is too small: direct conv, fp32.
__global__ __launch_bounds__(256) void naive_conv(const float* __restrict__ f,
                                                  const float* __restrict__ w,
                                                  const int* __restrict__ hi,
                                                  const int* __restrict__ wi,
                                                  float* __restrict__ out) {
  int idx = blockIdx.x * 256 + threadIdx.x;
  int n = idx & (NPTS - 1);
  int co = idx >> 16;
  int bh = hi[n] - 1;
  int bw = wi[n] - 1;
  float acc = 0.f;
  for (int ci = 0; ci < CIN; ++ci) {
    const float* fc = f + (size_t)ci * 262144;
    const float* wc = w + (size_t)co * 2304 + ci * 9;
#pragma unroll
    for (int t = 0; t < 9; ++t) {
      int y = bh + t / 3, x = bw + t % 3;
      float v = (y >= 0 && y < 512 && x >= 0 && x < 512) ? fc[y * 512 + x] : 0.f;
      acc += wc[t] * v;
    }
  }
  out[(size_t)co * NPTS + n] = acc;
}

extern "C" void kernel_launch(void* const* d_in, const int* in_sizes, int n_in,
                              void* d_out, int out_size, void* d_ws, size_t ws_size,
                              hipStream_t stream) {
  const float* feature = (const float*)d_in[0];
  const float* weight  = (const float*)d_in[1];
  const int* hidx      = (const int*)d_in[2];
  const int* widx      = (const int*)d_in[3];
  float* out           = (float*)d_out;

  const size_t FT_OFF = 2ull * 1024 * 1024;
  const size_t FT_BYTES = (size_t)NPIX * 256 * 2;   // ~135 MiB
  const size_t NEED = FT_OFF + FT_BYTES;

  if (ws_size >= NEED) {
    unsigned short* Abf = (unsigned short*)d_ws;    // 1.125 MiB
    unsigned short* Ft = (unsigned short*)((char*)d_ws + FT_OFF);
    prep_weight<<<(NKT * 16384) / 256, 256, 0, stream>>>(weight, Abf);
    border_zero<<<(2052 * 32 + 255) / 256, 256, 0, stream>>>(Ft);
    transpose_feat<<<262144 / 64, 256, 0, stream>>>(feature, Ft);
    gemm_gather<<<NPTS / 256, 512, 0, stream>>>(Abf, Ft, hidx, widx, out);
  } else {
    naive_conv<<<(COUT * NPTS) / 256, 256, 0, stream>>>(feature, weight, hidx, widx, out);
  }
}